// Round 12
// baseline (1184.622 us; speedup 1.0000x reference)
//
#include <hip/hip_runtime.h>
#include <hip/hip_bf16.h>
#include <math.h>

typedef unsigned short u16;
typedef unsigned int u32;
typedef __attribute__((ext_vector_type(8))) short short8;
typedef __attribute__((ext_vector_type(4))) float f32x4;
typedef __attribute__((ext_vector_type(4))) unsigned short u16x4;

__device__ __forceinline__ u16 f2b(float f) {
  u32 u = __builtin_bit_cast(u32, f);
  u = (u + 0x7fffu + ((u >> 16) & 1u)) >> 16;   // RNE
  return (u16)u;
}
__device__ __forceinline__ float b2f(u16 s) {
  return __builtin_bit_cast(float, (u32)s << 16);
}

// async global->LDS, 16B per lane; LDS dest = wave-uniform base + lane*16
__device__ __forceinline__ void ld_g2l(const u16* g, u16* l) {
  __builtin_amdgcn_global_load_lds(
      (const __attribute__((address_space(1))) unsigned int*)g,
      (__attribute__((address_space(3))) unsigned int*)l, 16, 0, 0);
}

// ---------------------------------------------------------------------------
// rope phase in REVOLUTIONS: freq_rev(n) = 2^(-(n&~1)/512) / (2pi).
// ---------------------------------------------------------------------------
__device__ __forceinline__ float rope_frev(int n) {
  return exp2f((float)(-(n & ~1)) * (1.0f / 512.0f)) * 0.15915494f;
}
__device__ __forceinline__ void rope_cs_fast(float frev, int t, float& c, float& s) {
  float ph = (float)t * frev;
  ph -= floorf(ph);                          // -> [0,1) revolutions
#if __has_builtin(__builtin_amdgcn_sinf) && __has_builtin(__builtin_amdgcn_cosf)
  s = __builtin_amdgcn_sinf(ph);             // sin(2*pi*ph)
  c = __builtin_amdgcn_cosf(ph);
#else
  __sincosf(ph * 6.2831853f, &s, &c);
#endif
}

// ---------------------------------------------------------------------------
// Core 128x128 tile GEMM (256 threads, 4 waves of 64x64), BK=64 staged as
// two pitch-32 8KiB buffer pairs per iteration; 32 KiB LDS keeps >=2
// blocks/CU so cross-block overlap hides drains. Requires Klen % 64 == 0.
// ---------------------------------------------------------------------------
__device__ __forceinline__ void gemm_core(
    const u16* __restrict__ A, const u16* __restrict__ B,
    int lda, int ldb, int Klen, int kb, int bm, int bn,
    u16* __restrict__ As, u16* __restrict__ Bs, f32x4 (&acc)[4][4])
{
  int tid = threadIdx.x;
  int w = tid >> 6, lane = tid & 63;
  int srow = (w << 4) + (lane >> 2);       // 0..63
  int scol = (lane & 3) << 3;              // element 0,8,16,24
  const u16* ga0 = A + (long)(bm * 128 + srow) * lda + kb + scol;
  const u16* ga1 = ga0 + (long)64 * lda;
  const u16* gb0 = B + (long)(bn * 128 + srow) * ldb + kb + scol;
  const u16* gb1 = gb0 + (long)64 * ldb;
  u16* la0 = As + (w << 9);  u16* la1 = la0 + 2048;
  u16* lb0 = Bs + (w << 9);  u16* lb1 = lb0 + 2048;

  int wm = (w >> 1) << 6, wn = (w & 1) << 6;
  int lane15 = lane & 15, quad = lane >> 4;
  const u16* ar = As + (wm + lane15) * 32 + quad * 8;
  const u16* br = Bs + (wn + lane15) * 32 + quad * 8;

#pragma unroll
  for (int i = 0; i < 4; i++)
#pragma unroll
    for (int j = 0; j < 4; j++) { f32x4 z = {0.f, 0.f, 0.f, 0.f}; acc[i][j] = z; }

  for (int k = 0; k < Klen; k += 64) {
    ld_g2l(ga0 + k, la0);
    ld_g2l(ga1 + k, la1);
    ld_g2l(gb0 + k, lb0);
    ld_g2l(gb1 + k, lb1);
    ld_g2l(ga0 + k + 32, la0 + 4096);
    ld_g2l(ga1 + k + 32, la1 + 4096);
    ld_g2l(gb0 + k + 32, lb0 + 4096);
    ld_g2l(gb1 + k + 32, lb1 + 4096);
    __syncthreads();
#pragma unroll
    for (int h = 0; h < 2; h++) {
      short8 af[4], bfr[4];
#pragma unroll
      for (int mt = 0; mt < 4; mt++) af[mt] = *(const short8*)(ar + h * 4096 + mt * 16 * 32);
#pragma unroll
      for (int nt = 0; nt < 4; nt++) bfr[nt] = *(const short8*)(br + h * 4096 + nt * 16 * 32);
#pragma unroll
      for (int mt = 0; mt < 4; mt++)
#pragma unroll
        for (int nt = 0; nt < 4; nt++)
          acc[mt][nt] = __builtin_amdgcn_mfma_f32_16x16x32_bf16(af[mt], bfr[nt], acc[mt][nt], 0, 0, 0);
    }
    __syncthreads();
  }
}

// ---------------------------------------------------------------------------
// EPI: 0 = store f32
//      1 = relu -> rope -> bf16   (encoder GEMM producing QR directly)
//      3 = atomicAdd f32 (split-K)
//      4 = relu(acc) * unrope(C in-place) -> bf16  (xy over QR buffer)
// tri=1: A is strictly-lower-triangular -> clamp K at (bm+1)*128
// ---------------------------------------------------------------------------
template<int EPI>
__global__ __launch_bounds__(256, 2) void gemm_bt(
    const u16* __restrict__ A, const u16* __restrict__ B, void* __restrict__ C,
    int K, int lda, int ldb, int ldc, int nsplits, long aB, long bB, long cB,
    int tri)
{
  __shared__ __align__(16) u16 As[2 * 128 * 32];   // 16 KiB
  __shared__ __align__(16) u16 Bs[2 * 128 * 32];   // 16 KiB
  int bn = blockIdx.x, bm = blockIdx.y;
  int batch = blockIdx.z / nsplits, sp = blockIdx.z % nsplits;
  int Klen = K / nsplits, kb = sp * Klen;
  if (tri) {
    int kend = (bm + 1) * 128;               // A cols >= kend are all zero
    if (kb >= kend) return;                  // nothing to add (EPI==3 path)
    if (kb + Klen > kend) Klen = kend - kb;  // multiple of 128 by construction
  }

  f32x4 acc[4][4];
  gemm_core(A + (long)batch * aB, B + (long)batch * bB, lda, ldb, Klen, kb, bm, bn, As, Bs, acc);

  int lane = threadIdx.x & 63, w = threadIdx.x >> 6;
  int wm = (w >> 1) << 6, wn = (w & 1) << 6;
  int lane15 = lane & 15, quad = lane >> 4;

  // hoisted rope frequencies (gn depends on nt only): 4 exp2f per thread
  float frev[4] = {0.f, 0.f, 0.f, 0.f};
  if (EPI == 1 || EPI == 4) {
#pragma unroll
    for (int nt = 0; nt < 4; nt++)
      frev[nt] = rope_frev(bn * 128 + wn + nt * 16 + lane15);
  }

#pragma unroll
  for (int mt = 0; mt < 4; mt++)
#pragma unroll
    for (int nt = 0; nt < 4; nt++) {
      int gn = bn * 128 + wn + nt * 16 + lane15;
#pragma unroll
      for (int r = 0; r < 4; r++) {
        int gm = bm * 128 + wm + mt * 16 + quad * 4 + r;
        float v = acc[mt][nt][r];
        long ci = (long)batch * cB + (long)gm * ldc + gn;
        if (EPI == 0) {
          ((float*)C)[ci] = v;
        } else if (EPI == 1) {
          float rv = fmaxf(v, 0.f);
          float ro = __shfl_xor(rv, 1);
          float c, s; rope_cs_fast(frev[nt], gm, c, s);
          float out = (gn & 1) ? (rv * c + ro * s) : (rv * c - ro * s);
          ((u16*)C)[ci] = f2b(out);
        } else if (EPI == 3) {
          atomicAdd(&((float*)C)[ci], v);
        } else if (EPI == 4) {
          u16* Cp = (u16*)C;
          float q = b2f(Cp[ci]);
          float qo = __shfl_xor(q, 1);
          float c, s; rope_cs_fast(frev[nt], gm, c, s);
          float xs = (gn & 1) ? (q * c - qo * s) : (q * c + qo * s);   // un-rope
          Cp[ci] = f2b(fmaxf(v, 0.f) * xs);
        }
      }
    }
}

// ---------------------------------------------------------------------------
// 8-phase counted-vmcnt pipeline macros (T3+T4+T5), verified in gemm_scores8.
// ---------------------------------------------------------------------------
#define SC_BAR   __builtin_amdgcn_s_barrier()
#define SC_LGKM0 asm volatile("s_waitcnt lgkmcnt(0)" ::: "memory")
#define SC_LGKM8 asm volatile("s_waitcnt lgkmcnt(8)" ::: "memory")
#define SC_VMF   do { asm volatile("s_waitcnt vmcnt(4)" ::: "memory"); \
                      __builtin_amdgcn_sched_barrier(0); } while (0)
#define SC_P1    __builtin_amdgcn_s_setprio(1)
#define SC_P0    __builtin_amdgcn_s_setprio(0)

#define DSA(Ab, mh) { \
  _Pragma("unroll") for (int mt = 0; mt < 4; mt++) { \
    aA[mt][0] = *(const short8*)((Ab) + ((mh) * 64 + mt * 16) * 64 + koff0); \
    aA[mt][1] = *(const short8*)((Ab) + ((mh) * 64 + mt * 16) * 64 + koff1); } }

#define DSB(Bb, nh, dst) { \
  _Pragma("unroll") for (int nt = 0; nt < 2; nt++) { \
    dst[nt][0] = *(const short8*)((Bb) + ((nh) * 32 + nt * 16) * 64 + koff0); \
    dst[nt][1] = *(const short8*)((Bb) + ((nh) * 32 + nt * 16) * 64 + koff1); } }

#define MMA(MH, NH, BB) { \
  _Pragma("unroll") for (int mt = 0; mt < 4; mt++) \
  _Pragma("unroll") for (int nt = 0; nt < 2; nt++) { \
    acc[(MH)*4+mt][(NH)*2+nt] = __builtin_amdgcn_mfma_f32_16x16x32_bf16( \
        aA[mt][0], BB[nt][0], acc[(MH)*4+mt][(NH)*2+nt], 0, 0, 0); \
    acc[(MH)*4+mt][(NH)*2+nt] = __builtin_amdgcn_mfma_f32_16x16x32_bf16( \
        aA[mt][1], BB[nt][1], acc[(MH)*4+mt][(NH)*2+nt], 0, 0, 0); } }

// Shared 8-phase body over K-tiles [kb, kb+nkt) (global kt indices; nkt even).
// vmcnt(4) fences at P4/P8 keep exactly 4 loads in flight across each barrier.
// Tail kt clamps to kb+nkt-1: duplicate stages land in buffers never read
// again (same WAR discipline), preserving the fence ledger.
#define SCORES_K_LOOP(kb, nkt) \
  for (int i = 0; i < (nkt) / 2; i++) { \
    int kt1 = (kb) + 2 * i + 1; \
    int kt2 = 2 * i + 2; if (kt2 > (nkt) - 1) kt2 = (nkt) - 1; kt2 += (kb); \
    int kt3 = 2 * i + 3; if (kt3 > (nkt) - 1) kt3 = (nkt) - 1; kt3 += (kb); \
    short8 aA[4][2], bb0[2][2], bb1[2][2]; \
    /* P1 */ \
    DSA(A0, 0); DSB(B0, 0, bb0); \
    STG(gA, &Abuf[1][0], kt1); \
    SC_LGKM8; SC_BAR; SC_LGKM0; SC_P1; MMA(0, 0, bb0); SC_P0; SC_BAR; \
    /* P2 */ \
    DSB(B0, 1, bb1); \
    STG(gA + HSTEP, &Abuf[1][128 * 64], kt1); \
    SC_BAR; SC_LGKM0; SC_P1; MMA(0, 1, bb1); SC_P0; SC_BAR; \
    /* P3 */ \
    DSA(A0, 1); \
    STG(gB, &Bbuf[0][0], kt2); \
    SC_BAR; SC_LGKM0; SC_P1; MMA(1, 1, bb1); SC_P0; SC_BAR; \
    /* P4 */ \
    STG(gB + HSTEP, &Bbuf[0][128 * 64], kt2); \
    SC_VMF; SC_BAR; SC_LGKM0; SC_P1; MMA(1, 0, bb0); SC_P0; SC_BAR; \
    /* P5 */ \
    DSA(A1, 0); DSB(B1, 0, bb0); \
    STG(gA, &Abuf[0][0], kt2); \
    SC_LGKM8; SC_BAR; SC_LGKM0; SC_P1; MMA(0, 0, bb0); SC_P0; SC_BAR; \
    /* P6 */ \
    DSB(B1, 1, bb1); \
    STG(gA + HSTEP, &Abuf[0][128 * 64], kt2); \
    SC_BAR; SC_LGKM0; SC_P1; MMA(0, 1, bb1); SC_P0; SC_BAR; \
    /* P7 */ \
    DSA(A1, 1); \
    STG(gB, &Bbuf[1][0], kt3); \
    SC_BAR; SC_LGKM0; SC_P1; MMA(1, 1, bb1); SC_P0; SC_BAR; \
    /* P8 */ \
    STG(gB + HSTEP, &Bbuf[1][128 * 64], kt3); \
    SC_VMF; SC_BAR; SC_LGKM0; SC_P1; MMA(1, 0, bb0); SC_P0; SC_BAR; \
  }

// common per-block setup for the scores kernels
#define SCORES_SETUP \
  int tid = threadIdx.x; \
  int w = tid >> 6, lane = tid & 63; \
  int wr = w >> 2, wc = w & 3; \
  int lane15 = lane & 15, quad = lane >> 4; \
  int swz = lane15 & 7; \
  int koff0 = ((quad) ^ swz) << 3; \
  int koff1 = ((4 + quad) ^ swz) << 3; \
  const u16* gA = Q + (long)(bm * 256) * 8192; \
  const u16* gB = Q + (long)(bn * 256) * 8192; \
  const u16* A0 = &Abuf[0][(wr * 128 + lane15) * 64]; \
  const u16* A1 = &Abuf[1][(wr * 128 + lane15) * 64]; \
  const u16* B0 = &Bbuf[0][(wc * 64 + lane15) * 64]; \
  const u16* B1 = &Bbuf[1][(wc * 64 + lane15) * 64]; \
  int sr = lane >> 3, sc = lane & 7; \
  long g_sk = (long)sr * 8192 + ((sc ^ sr) << 3); \
  int l_base = (w * 16) * 64; \
  long g_wrow = (long)(w * 16) * 8192; \
  auto STG = [&](const u16* gHalfBase, u16* lHalfBase, int kt) { \
    const u16* g = gHalfBase + g_wrow + g_sk + (long)kt * 64; \
    u16* l = lHalfBase + l_base; \
    ld_g2l(g, l); \
    ld_g2l(g + (long)8 * 8192, l + 8 * 64); \
  }; \
  f32x4 acc[8][4]; \
  _Pragma("unroll") \
  for (int i2 = 0; i2 < 8; i2++) \
  _Pragma("unroll") \
    for (int j = 0; j < 4; j++) { f32x4 z = {0.f, 0.f, 0.f, 0.f}; acc[i2][j] = z; } \
  const long HSTEP = (long)128 * 8192;

__device__ __forceinline__ void tri_decode(int q, int& bm, int& bn) {
  bm = (int)((sqrtf(8.f * (float)q + 1.f) - 1.f) * 0.5f);
  while ((bm + 1) * (bm + 2) / 2 <= q) bm++;
  while (bm * (bm + 1) / 2 > q) bm--;
  bn = q - bm * (bm + 1) / 2;
}

__device__ __forceinline__ int xcd_remap(int lin, int total) {
  int cpx = total >> 3, rr = total & 7;
  int xcd = lin & 7, ii = lin >> 3;
  return (xcd < rr) ? xcd * (cpx + 1) + ii
                    : rr * (cpx + 1) + (xcd - rr) * cpx + ii;
}

// ---------------------------------------------------------------------------
// scores fallback (ws-tight): full-K 256^2 tril tiles, direct bf16 store.
// Verified rounds 6/10: FETCH ~115 MB, ~220 us/dispatch at HB=4.
// ---------------------------------------------------------------------------
__global__ __launch_bounds__(512, 1) void gemm_scores8(
    const u16* __restrict__ QR, u16* __restrict__ S, int T, int ntri)
{
  __shared__ __align__(16) u16 Abuf[2][256 * 64];   // 64 KiB
  __shared__ __align__(16) u16 Bbuf[2][256 * 64];   // 64 KiB

  int c = xcd_remap(blockIdx.x, gridDim.x);
  int zh = c / ntri, q = c % ntri;
  int bm, bn; tri_decode(q, bm, bn);

  const u16* Q = QR + (long)zh * (long)T * 8192;
  u16* Sb = S + (long)zh * (long)T * T;

  SCORES_SETUP

  STG(gA, &Abuf[0][0], 0); STG(gA + HSTEP, &Abuf[0][128 * 64], 0);
  STG(gB, &Bbuf[0][0], 0); STG(gB + HSTEP, &Bbuf[0][128 * 64], 0);
  STG(gB, &Bbuf[1][0], 1); STG(gB + HSTEP, &Bbuf[1][128 * 64], 1);
  SC_VMF;
  SC_BAR;

  SCORES_K_LOOP(0, 128)

#pragma unroll
  for (int mt = 0; mt < 8; mt++)
#pragma unroll
    for (int nt = 0; nt < 4; nt++) {
      int gn = bn * 256 + wc * 64 + nt * 16 + lane15;
#pragma unroll
      for (int r = 0; r < 4; r++) {
        int gm = bm * 256 + wr * 128 + mt * 16 + quad * 4 + r;
        Sb[(long)gm * T + gn] = f2b(gm > gn ? acc[mt][nt][r] : 0.f);
      }
    }
}

// ---------------------------------------------------------------------------
// scores K-split x3 with PACKED-TRIL f32 partials: fixes grid quantization
// (144 blocks on 256 CUs = 56% fill) without the full-T^2 buffer that
// failed to fit in round 11. Partials live in a packed buffer of
// HC*ntri tiles x 256x256 f32 (256 KB/tile) that aliases yKV_f32's region
// (disjoint liveness). 3 splits (44/44/40 K-tiles, all even) atomicAdd into
// the tile; tril_cvt applies the strict-lower mask and converts to the
// strided bf16 scores buffer. Adjacent splits share panels under the XCD
// remap (L2-local; round-6-verified), and the packed region is ~2.4 MB/XCD
// -> atomics are L2-resident.
// ---------------------------------------------------------------------------
__global__ __launch_bounds__(512, 1) void gemm_scores_k3(
    const u16* __restrict__ QR, float* __restrict__ Sf, int T, int ntri)
{
  __shared__ __align__(16) u16 Abuf[2][256 * 64];   // 64 KiB
  __shared__ __align__(16) u16 Bbuf[2][256 * 64];   // 64 KiB

  int c = xcd_remap(blockIdx.x, gridDim.x);
  int sp = c % 3, c2 = c / 3;
  int zh = c2 / ntri, q = c2 % ntri;
  int bm, bn; tri_decode(q, bm, bn);

  int kb = sp * 44;                        // K-tile base (units of 64)
  int nkt = (sp == 2) ? 40 : 44;           // 44+44+40 = 128; all even

  const u16* Q = QR + (long)zh * (long)T * 8192;
  float* tb = Sf + ((long)(zh * ntri + q) << 16);   // packed 256x256 tile

  SCORES_SETUP

  STG(gA, &Abuf[0][0], kb); STG(gA + HSTEP, &Abuf[0][128 * 64], kb);
  STG(gB, &Bbuf[0][0], kb); STG(gB + HSTEP, &Bbuf[0][128 * 64], kb);
  STG(gB, &Bbuf[1][0], kb + 1); STG(gB + HSTEP, &Bbuf[1][128 * 64], kb + 1);
  SC_VMF;
  SC_BAR;

  SCORES_K_LOOP(kb, nkt)

  // epilogue: f32 atomic accumulate into the packed tile (mask in tril_cvt)
#pragma unroll
  for (int mt = 0; mt < 8; mt++)
#pragma unroll
    for (int nt = 0; nt < 4; nt++) {
      int ct = wc * 64 + nt * 16 + lane15;
#pragma unroll
      for (int r = 0; r < 4; r++) {
        int rt = wr * 128 + mt * 16 + quad * 4 + r;
        atomicAdd(&tb[rt * 256 + ct], acc[mt][nt][r]);
      }
    }
}

// tril mask + packed f32 -> strided bf16. grid.x = HC*ntri*8 (8 row-bands
// of 32 per tile), 256 threads; each block converts one 32x256 band.
__global__ __launch_bounds__(256) void tril_cvt(
    const float* __restrict__ Sf, u16* __restrict__ Sb, int T, int ntri)
{
  int bx = blockIdx.x;
  int tl = bx >> 3, chunk = bx & 7;
  int zh = tl / ntri, q = tl % ntri;
  int bm, bn; tri_decode(q, bm, bn);
  const float* f = Sf + ((long)tl << 16);
  u16* b = Sb + (long)zh * (long)T * T;
  int tid = threadIdx.x;
  int rsub = tid >> 6;                     // 0..3
  int lc = (tid & 63) * 4;                 // col within tile (f32x4 lanes)
#pragma unroll
  for (int it = 0; it < 8; it++) {
    int rt = chunk * 32 + it * 4 + rsub;   // row within tile
    int gm = bm * 256 + rt;
    int gn0 = bn * 256 + lc;
    f32x4 v = *(const f32x4*)(f + rt * 256 + lc);
    u16x4 w2;
#pragma unroll
    for (int r = 0; r < 4; r++)
      w2[r] = (gm > gn0 + r) ? f2b(v[r]) : (u16)0;
    *(u16x4*)(b + (long)gm * T + gn0) = w2;
  }
}

// ---------------------------------------------------------------------------
__global__ __launch_bounds__(256) void trans_f32_bf16(
    const float* __restrict__ src, u16* __restrict__ dst, int R, int C)
{
  __shared__ float tile[32][33];
  long off = (long)blockIdx.z * R * C;
  const float* s = src + off;
  u16* d = dst + off;
  int lx = threadIdx.x & 31, ly = threadIdx.x >> 5;
  int c = blockIdx.x * 32 + lx;
#pragma unroll
  for (int p = 0; p < 32; p += 8)
    tile[ly + p][lx] = s[(long)(blockIdx.y * 32 + ly + p) * C + c];
  __syncthreads();
  int rr = blockIdx.y * 32 + lx;
#pragma unroll
  for (int p = 0; p < 32; p += 8)
    d[(long)(blockIdx.x * 32 + ly + p) * R + rr] = f2b(tile[lx][ly + p]);
}

__device__ __forceinline__ float block_sum(float v, float* red) {
#pragma unroll
  for (int o = 32; o > 0; o >>= 1) v += __shfl_down(v, o, 64);
  int lane = threadIdx.x & 63, wid = threadIdx.x >> 6;
  if (lane == 0) red[wid] = v;
  __syncthreads();
  float r = red[0] + red[1] + red[2] + red[3];
  __syncthreads();
  return r;
}

__global__ __launch_bounds__(256) void embed_ln(
    const int* __restrict__ idx, const float* __restrict__ embed,
    float* __restrict__ x, u16* __restrict__ xb, u16* __restrict__ xT, int T)
{
  __shared__ float red[4];
  int t = blockIdx.x, d = threadIdx.x;
  float v = embed[(long)idx[t] * 256 + d];
  float mu = block_sum(v, red) * (1.f / 256.f);
  float c = v - mu;
  float var = block_sum(c * c, red) * (1.f / 256.f);
  float o = c * rsqrtf(var + 1e-5f);
  x[(long)t * 256 + d] = o;
  xb[(long)t * 256 + d] = f2b(o);
  xT[(long)d * T + t] = f2b(o);
}

__global__ __launch_bounds__(256) void row_ln(
    const float* __restrict__ in, u16* __restrict__ out)
{
  __shared__ float red[4];
  long row = blockIdx.x;
  int d = threadIdx.x;
  float v = in[row * 256 + d];
  float mu = block_sum(v, red) * (1.f / 256.f);
  float c = v - mu;
  float var = block_sum(c * c, red) * (1.f / 256.f);
  out[row * 256 + d] = f2b(c * rsqrtf(var + 1e-5f));
}

__global__ __launch_bounds__(256) void resid_ln(
    const float* __restrict__ yMLP, float* __restrict__ x,
    u16* __restrict__ xb, u16* __restrict__ xT, int T)
{
  __shared__ float red[4];
  int t = blockIdx.x, d = threadIdx.x;
  float y = yMLP[(long)t * 256 + d];
  float mu1 = block_sum(y, red) * (1.f / 256.f);
  float c1 = y - mu1;
  float var1 = block_sum(c1 * c1, red) * (1.f / 256.f);
  float l1 = c1 * rsqrtf(var1 + 1e-5f);
  float v = x[(long)t * 256 + d] + l1;
  float mu2 = block_sum(v, red) * (1.f / 256.f);
  float c2 = v - mu2;
  float var2 = block_sum(c2 * c2, red) * (1.f / 256.f);
  float o = c2 * rsqrtf(var2 + 1e-5f);
  x[(long)t * 256 + d] = o;
  xb[(long)t * 256 + d] = f2b(o);
  xT[(long)d * T + t] = f2b(o);
}

// ---------------------------------------------------------------------------
extern "C" void kernel_launch(void* const* d_in, const int* in_sizes, int n_in,
                              void* d_out, int out_size, void* d_ws, size_t ws_size,
                              hipStream_t stream) {
  const int*   idx       = (const int*)d_in[0];
  const float* embed     = (const float*)d_in[1];
  const float* encoder   = (const float*)d_in[2];
  const float* encoder_v = (const float*)d_in[3];
  const float* decoder   = (const float*)d_in[4];
  const float* lm_head   = (const float*)d_in[5];
  const int T = in_sizes[0];                 // 2048
  const int D = 256, NH = 4, Nn = 8192, V = 256;

  char* ws = (char*)d_ws;
  size_t off = 0;
  auto alloc = [&](size_t bytes) -> void* {
    void* p = ws + off; off += (bytes + 255) & ~(size_t)255; return p;
  };
  float* x_f32   = (float*)alloc((size_t)T * D * 4);
  float* yMLP    = (float*)alloc((size_t)T * D * 4);
  u16* x_b    = (u16*)alloc((size_t)T * D * 2);
  u16* xT     = (u16*)alloc((size_t)T * D * 2);
  u16* yKV_b  = (u16*)alloc((size_t)NH * T * D * 2);
  u16* lmT    = (u16*)alloc((size_t)D * V * 2);
  u16* encT   = (u16*)alloc((size_t)NH * Nn * D * 2);
  u16* encvT  = (u16*)alloc((size_t)NH * Nn * D * 2);
  u16* decT   = (u16*)alloc((size_t)D * NH * Nn * 2);
  // head-batch ladder: pick largest HB in {4,2,1} whose QR+scores fit
  // (+8MB for the yKV_f32 floor of the union region)
  size_t per_head = ((size_t)T * T * 2 + 256) + ((size_t)T * Nn * 2 + 256);
  size_t yKVbytes = (size_t)NH * T * D * 4;
  int HB = 4;
  while (HB > 1 && off + (size_t)HB * per_head + yKVbytes + 256 > ws_size) HB >>= 1;
  u16* scores = (u16*)alloc((size_t)HB * T * T * 2);
  u16* QRxy   = (u16*)alloc((size_t)HB * T * Nn * 2);

  const int nbm = T / 256, ntri = nbm * (nbm + 1) / 2;   // tril 256-tiles

  // union region U: yKV_f32 (always) ∪ packed-tril f32 scores partials.
  // HC ladder: largest HC in {HB, HB/2, ...} >= 2 whose packed buffer fits.
  int HC = HB;
  size_t uBytes = yKVbytes;
  while (HC >= 2) {
    size_t need = (size_t)HC * ntri * 65536 * 4;
    if (need < yKVbytes) need = yKVbytes;
    if (off + need + 256 <= ws_size) { uBytes = need; break; }
    HC >>= 1;
  }
  if (HC < 2) HC = 0;                      // fallback: gemm_scores8
  float* U = (float*)alloc(uBytes);
  float* yKV_f32 = U;
  float* scoresF = U;
  if (off > ws_size) return;

  // one-time weight prep: transpose to K-major bf16
  trans_f32_bf16<<<dim3(Nn / 32, D / 32, NH), 256, 0, stream>>>(encoder, encT, D, Nn);
  trans_f32_bf16<<<dim3(Nn / 32, D / 32, NH), 256, 0, stream>>>(encoder_v, encvT, D, Nn);
  trans_f32_bf16<<<dim3(D / 32, (NH * Nn) / 32, 1), 256, 0, stream>>>(decoder, decT, NH * Nn, D);
  trans_f32_bf16<<<dim3(V / 32, D / 32, 1), 256, 0, stream>>>(lm_head, lmT, D, V);

  embed_ln<<<T, 256, 0, stream>>>(idx, embed, x_f32, x_b, xT, T);

  for (int l = 0; l < 2; l++) {
    hipMemsetAsync(yMLP, 0, (size_t)T * D * 4, stream);
    for (int h0 = 0; h0 < NH; h0 += HB) {
      // QR = rope(relu(x @ encoder[h]))  (rope fused in epilogue)
      gemm_bt<1><<<dim3(Nn / 128, T / 128, HB), 256, 0, stream>>>(
          x_b, encT + (size_t)h0 * Nn * D, QRxy,
          D, D, D, Nn, 1, 0L, (long)Nn * D, (long)T * Nn, 0);
      // scores = tril(QR QR^T, -1)
      if (HC > 0) {
        // K-split x3 into packed-tril f32 partials, per HC-chunk of heads
        for (int hc = 0; hc < HB; hc += HC) {
          hipMemsetAsync(scoresF, 0, (size_t)HC * ntri * 65536 * 4, stream);
          gemm_scores_k3<<<dim3(ntri * HC * 3, 1, 1), 512, 0, stream>>>(
              QRxy + (size_t)hc * T * Nn, scoresF, T, ntri);
          tril_cvt<<<dim3(HC * ntri * 8, 1, 1), 256, 0, stream>>>(
              scoresF, scores + (size_t)hc * (size_t)T * T, T, ntri);
        }
      } else {
        gemm_scores8<<<dim3(ntri * HB, 1, 1), 512, 0, stream>>>(
            QRxy, scores, T, ntri);
      }
      // yKV = scores @ x (split-K=8, atomic f32, triangular K-clamp)
      hipMemsetAsync(yKV_f32, 0, (size_t)HB * T * D * 4, stream);
      gemm_bt<3><<<dim3(D / 128, T / 128, HB * 8), 256, 0, stream>>>(
          scores, xT, yKV_f32,
          T, T, T, D, 8, (long)T * T, 0L, (long)T * D, 1);
      // yKV = ln(yKV)
      row_ln<<<HB * T, 256, 0, stream>>>(yKV_f32, yKV_b);
      // xy = relu(yKV @ encoder_v[h]) * unrope(QR), in-place over QR
      gemm_bt<4><<<dim3(Nn / 128, T / 128, HB), 256, 0, stream>>>(
          yKV_b, encvT + (size_t)h0 * Nn * D, QRxy,
          D, D, D, Nn, 1, (long)T * D, (long)Nn * D, (long)T * Nn, 0);
      // yMLP += xy @ decoder[h]  (split-K=4, atomic f32)
      gemm_bt<3><<<dim3(D / 128, T / 128, HB * 4), 256, 0, stream>>>(
          QRxy, decT + (size_t)h0 * Nn, yMLP,
          Nn, Nn, NH * Nn, D, 4, (long)T * Nn, (long)Nn, 0L, 0);
    }
    resid_ln<<<T, 256, 0, stream>>>(yMLP, x_f32, x_b, xT, T);
  }

  // logits = x @ lm_head (f32 out)
  gemm_bt<0><<<dim3(V / 128, T / 128, 1), 256, 0, stream>>>(
      x_b, lmT, d_out, D, D, D, V, 1, 0L, 0L, 0L, 0);
}

// Round 13
// 1135.417 us; speedup vs baseline: 1.0433x; 1.0433x over previous
//
#include <hip/hip_runtime.h>
#include <hip/hip_bf16.h>
#include <math.h>

typedef unsigned short u16;
typedef unsigned int u32;
typedef __attribute__((ext_vector_type(8))) short short8;
typedef __attribute__((ext_vector_type(4))) float f32x4;

__device__ __forceinline__ u16 f2b(float f) {
  u32 u = __builtin_bit_cast(u32, f);
  u = (u + 0x7fffu + ((u >> 16) & 1u)) >> 16;   // RNE
  return (u16)u;
}
__device__ __forceinline__ float b2f(u16 s) {
  return __builtin_bit_cast(float, (u32)s << 16);
}

// async global->LDS, 16B per lane; LDS dest = wave-uniform base + lane*16
__device__ __forceinline__ void ld_g2l(const u16* g, u16* l) {
  __builtin_amdgcn_global_load_lds(
      (const __attribute__((address_space(1))) unsigned int*)g,
      (__attribute__((address_space(3))) unsigned int*)l, 16, 0, 0);
}

// ---------------------------------------------------------------------------
// rope phase in REVOLUTIONS: freq_rev(n) = 2^(-(n&~1)/512) / (2pi).
// v_sin_f32 / v_cos_f32 take revolutions directly (reduce with fract first).
// ---------------------------------------------------------------------------
__device__ __forceinline__ float rope_frev(int n) {
  return exp2f((float)(-(n & ~1)) * (1.0f / 512.0f)) * 0.15915494f;
}
__device__ __forceinline__ void rope_cs_fast(float frev, int t, float& c, float& s) {
  float ph = (float)t * frev;
  ph -= floorf(ph);                          // -> [0,1) revolutions
#if __has_builtin(__builtin_amdgcn_sinf) && __has_builtin(__builtin_amdgcn_cosf)
  s = __builtin_amdgcn_sinf(ph);             // sin(2*pi*ph)
  c = __builtin_amdgcn_cosf(ph);
#else
  __sincosf(ph * 6.2831853f, &s, &c);
#endif
}

// ---------------------------------------------------------------------------
// Core 128x128 tile GEMM (256 threads, 4 waves of 64x64), BK=64 staged as
// two pitch-32 8KiB buffer pairs per iteration; 32 KiB LDS keeps >=2
// blocks/CU so cross-block overlap hides drains. Requires Klen % 64 == 0.
// ---------------------------------------------------------------------------
__device__ __forceinline__ void gemm_core(
    const u16* __restrict__ A, const u16* __restrict__ B,
    int lda, int ldb, int Klen, int kb, int bm, int bn,
    u16* __restrict__ As, u16* __restrict__ Bs, f32x4 (&acc)[4][4])
{
  int tid = threadIdx.x;
  int w = tid >> 6, lane = tid & 63;
  int srow = (w << 4) + (lane >> 2);       // 0..63
  int scol = (lane & 3) << 3;              // element 0,8,16,24
  const u16* ga0 = A + (long)(bm * 128 + srow) * lda + kb + scol;
  const u16* ga1 = ga0 + (long)64 * lda;
  const u16* gb0 = B + (long)(bn * 128 + srow) * ldb + kb + scol;
  const u16* gb1 = gb0 + (long)64 * ldb;
  u16* la0 = As + (w << 9);  u16* la1 = la0 + 2048;
  u16* lb0 = Bs + (w << 9);  u16* lb1 = lb0 + 2048;

  int wm = (w >> 1) << 6, wn = (w & 1) << 6;
  int lane15 = lane & 15, quad = lane >> 4;
  const u16* ar = As + (wm + lane15) * 32 + quad * 8;
  const u16* br = Bs + (wn + lane15) * 32 + quad * 8;

#pragma unroll
  for (int i = 0; i < 4; i++)
#pragma unroll
    for (int j = 0; j < 4; j++) { f32x4 z = {0.f, 0.f, 0.f, 0.f}; acc[i][j] = z; }

  for (int k = 0; k < Klen; k += 64) {
    // stage K-chunk k -> buffer 0, K-chunk k+32 -> buffer 1 (at +4096 u16)
    ld_g2l(ga0 + k, la0);
    ld_g2l(ga1 + k, la1);
    ld_g2l(gb0 + k, lb0);
    ld_g2l(gb1 + k, lb1);
    ld_g2l(ga0 + k + 32, la0 + 4096);
    ld_g2l(ga1 + k + 32, la1 + 4096);
    ld_g2l(gb0 + k + 32, lb0 + 4096);
    ld_g2l(gb1 + k + 32, lb1 + 4096);
    __syncthreads();
#pragma unroll
    for (int h = 0; h < 2; h++) {
      short8 af[4], bfr[4];
#pragma unroll
      for (int mt = 0; mt < 4; mt++) af[mt] = *(const short8*)(ar + h * 4096 + mt * 16 * 32);
#pragma unroll
      for (int nt = 0; nt < 4; nt++) bfr[nt] = *(const short8*)(br + h * 4096 + nt * 16 * 32);
#pragma unroll
      for (int mt = 0; mt < 4; mt++)
#pragma unroll
        for (int nt = 0; nt < 4; nt++)
          acc[mt][nt] = __builtin_amdgcn_mfma_f32_16x16x32_bf16(af[mt], bfr[nt], acc[mt][nt], 0, 0, 0);
    }
    __syncthreads();
  }
}

// ---------------------------------------------------------------------------
// EPI: 0 = store f32
//      1 = relu -> rope -> bf16   (encoder GEMM producing QR directly)
//      3 = atomicAdd f32 (split-K)
//      4 = relu(acc) * unrope(C in-place) -> bf16  (xy over QR buffer)
// tri=1: A is strictly-lower-triangular -> clamp K at (bm+1)*128
// ---------------------------------------------------------------------------
template<int EPI>
__global__ __launch_bounds__(256, 2) void gemm_bt(
    const u16* __restrict__ A, const u16* __restrict__ B, void* __restrict__ C,
    int K, int lda, int ldb, int ldc, int nsplits, long aB, long bB, long cB,
    int tri)
{
  __shared__ __align__(16) u16 As[2 * 128 * 32];   // 16 KiB
  __shared__ __align__(16) u16 Bs[2 * 128 * 32];   // 16 KiB
  int bn = blockIdx.x, bm = blockIdx.y;
  int batch = blockIdx.z / nsplits, sp = blockIdx.z % nsplits;
  int Klen = K / nsplits, kb = sp * Klen;
  if (tri) {
    int kend = (bm + 1) * 128;               // A cols >= kend are all zero
    if (kb >= kend) return;                  // nothing to add (EPI==3 path)
    if (kb + Klen > kend) Klen = kend - kb;  // multiple of 128 by construction
  }

  f32x4 acc[4][4];
  gemm_core(A + (long)batch * aB, B + (long)batch * bB, lda, ldb, Klen, kb, bm, bn, As, Bs, acc);

  int lane = threadIdx.x & 63, w = threadIdx.x >> 6;
  int wm = (w >> 1) << 6, wn = (w & 1) << 6;
  int lane15 = lane & 15, quad = lane >> 4;

  // hoisted rope frequencies (gn depends on nt only): 4 exp2f per thread
  float frev[4] = {0.f, 0.f, 0.f, 0.f};
  if (EPI == 1 || EPI == 4) {
#pragma unroll
    for (int nt = 0; nt < 4; nt++)
      frev[nt] = rope_frev(bn * 128 + wn + nt * 16 + lane15);
  }

#pragma unroll
  for (int mt = 0; mt < 4; mt++)
#pragma unroll
    for (int nt = 0; nt < 4; nt++) {
      int gn = bn * 128 + wn + nt * 16 + lane15;
#pragma unroll
      for (int r = 0; r < 4; r++) {
        int gm = bm * 128 + wm + mt * 16 + quad * 4 + r;
        float v = acc[mt][nt][r];
        long ci = (long)batch * cB + (long)gm * ldc + gn;
        if (EPI == 0) {
          ((float*)C)[ci] = v;
        } else if (EPI == 1) {
          float rv = fmaxf(v, 0.f);
          float ro = __shfl_xor(rv, 1);
          float c, s; rope_cs_fast(frev[nt], gm, c, s);
          float out = (gn & 1) ? (rv * c + ro * s) : (rv * c - ro * s);
          ((u16*)C)[ci] = f2b(out);
        } else if (EPI == 3) {
          atomicAdd(&((float*)C)[ci], v);
        } else if (EPI == 4) {
          u16* Cp = (u16*)C;
          float q = b2f(Cp[ci]);
          float qo = __shfl_xor(q, 1);
          float c, s; rope_cs_fast(frev[nt], gm, c, s);
          float xs = (gn & 1) ? (q * c - qo * s) : (q * c + qo * s);   // un-rope
          Cp[ci] = f2b(fmaxf(v, 0.f) * xs);
        }
      }
    }
}

// ---------------------------------------------------------------------------
// 8-phase counted-vmcnt pipeline macros (T3+T4+T5), verified in gemm_scores8.
// ---------------------------------------------------------------------------
#define SC_BAR   __builtin_amdgcn_s_barrier()
#define SC_LGKM0 asm volatile("s_waitcnt lgkmcnt(0)" ::: "memory")
#define SC_LGKM8 asm volatile("s_waitcnt lgkmcnt(8)" ::: "memory")
#define SC_VMF   do { asm volatile("s_waitcnt vmcnt(4)" ::: "memory"); \
                      __builtin_amdgcn_sched_barrier(0); } while (0)
#define SC_P1    __builtin_amdgcn_s_setprio(1)
#define SC_P0    __builtin_amdgcn_s_setprio(0)

#define DSA(Ab, mh) { \
  _Pragma("unroll") for (int mt = 0; mt < 4; mt++) { \
    aA[mt][0] = *(const short8*)((Ab) + ((mh) * 64 + mt * 16) * 64 + koff0); \
    aA[mt][1] = *(const short8*)((Ab) + ((mh) * 64 + mt * 16) * 64 + koff1); } }

#define DSB(Bb, nh, dst) { \
  _Pragma("unroll") for (int nt = 0; nt < 2; nt++) { \
    dst[nt][0] = *(const short8*)((Bb) + ((nh) * 32 + nt * 16) * 64 + koff0); \
    dst[nt][1] = *(const short8*)((Bb) + ((nh) * 32 + nt * 16) * 64 + koff1); } }

#define MMA(MH, NH, BB) { \
  _Pragma("unroll") for (int mt = 0; mt < 4; mt++) \
  _Pragma("unroll") for (int nt = 0; nt < 2; nt++) { \
    acc[(MH)*4+mt][(NH)*2+nt] = __builtin_amdgcn_mfma_f32_16x16x32_bf16( \
        aA[mt][0], BB[nt][0], acc[(MH)*4+mt][(NH)*2+nt], 0, 0, 0); \
    acc[(MH)*4+mt][(NH)*2+nt] = __builtin_amdgcn_mfma_f32_16x16x32_bf16( \
        aA[mt][1], BB[nt][1], acc[(MH)*4+mt][(NH)*2+nt], 0, 0, 0); } }

// ---------------------------------------------------------------------------
// scores = tril(QR QR^T, -1), 256x256 tiles, tril-only FLAT grid with
// bijective XCD-chunked swizzle: each XCD gets ~18 consecutive
// (head, tri-tile) indices -> its concurrent blocks share a handful of
// 256-row QR panels and sweep K in near-lockstep (FETCH 506->115 MB,
// verified round 6). 8 waves (2M x 4N), per-wave output 128x64, BK=64,
// dbuf 128 KiB LDS, both-sides XOR swizzle, counted vmcnt(4) at P4/P8.
// Structural ceiling ~220 us at HB=4 (rounds 6-12: thinner tiles, K-split,
// L2 swizzle, occupancy trades all measured and bounded).
// ---------------------------------------------------------------------------
__global__ __launch_bounds__(512, 1) void gemm_scores8(
    const u16* __restrict__ QR, u16* __restrict__ S, int T, int ntri)
{
  __shared__ __align__(16) u16 Abuf[2][256 * 64];   // 64 KiB
  __shared__ __align__(16) u16 Bbuf[2][256 * 64];   // 64 KiB

  // XCD-chunked bijective remap of the flat (head*ntri) index
  int total = gridDim.x;
  int lin = blockIdx.x;
  int cpx = total >> 3, rr = total & 7;
  int xcd = lin & 7, ii = lin >> 3;
  int c = (xcd < rr) ? xcd * (cpx + 1) + ii
                     : rr * (cpx + 1) + (xcd - rr) * cpx + ii;
  int zh = c / ntri, q = c % ntri;

  // decode lower-triangular tile index q -> (bm, bn), bn <= bm
  int bm = (int)((sqrtf(8.f * (float)q + 1.f) - 1.f) * 0.5f);
  while ((bm + 1) * (bm + 2) / 2 <= q) bm++;
  while (bm * (bm + 1) / 2 > q) bm--;
  int bn = q - bm * (bm + 1) / 2;

  const u16* Q = QR + (long)zh * (long)T * 8192;
  u16* Sb = S + (long)zh * (long)T * T;

  int tid = threadIdx.x;
  int w = tid >> 6, lane = tid & 63;
  int wr = w >> 2, wc = w & 3;                 // 2M x 4N wave grid
  int lane15 = lane & 15, quad = lane >> 4;
  int swz = lane15 & 7;
  int koff0 = ((quad) ^ swz) << 3;             // kf=0 swizzled slot (u16 units)
  int koff1 = ((4 + quad) ^ swz) << 3;         // kf=1

  const u16* gA = Q + (long)(bm * 256) * 8192;
  const u16* gB = Q + (long)(bn * 256) * 8192;

  const u16* A0 = &Abuf[0][(wr * 128 + lane15) * 64];
  const u16* A1 = &Abuf[1][(wr * 128 + lane15) * 64];
  const u16* B0 = &Bbuf[0][(wc * 64 + lane15) * 64];
  const u16* B1 = &Bbuf[1][(wc * 64 + lane15) * 64];

  // staging: lane covers row (w*16 + (lane>>3) [+8]), source k-slot
  // (lane&7)^(lane>>3) so the linear LDS write lands swizzled.
  int sr = lane >> 3, sc = lane & 7;
  long g_sk = (long)sr * 8192 + ((sc ^ sr) << 3);
  int l_base = (w * 16) * 64;
  long g_wrow = (long)(w * 16) * 8192;

  auto STG = [&](const u16* gHalfBase, u16* lHalfBase, int kt) {
    const u16* g = gHalfBase + g_wrow + g_sk + kt * 64;
    u16* l = lHalfBase + l_base;
    ld_g2l(g, l);
    ld_g2l(g + (long)8 * 8192, l + 8 * 64);
  };

  f32x4 acc[8][4];
#pragma unroll
  for (int i2 = 0; i2 < 8; i2++)
#pragma unroll
    for (int j = 0; j < 4; j++) { f32x4 z = {0.f, 0.f, 0.f, 0.f}; acc[i2][j] = z; }

  const long HSTEP = (long)128 * 8192;

  // prologue: buf0 <- kt0 (A+B), buf1.B <- kt1; keep 4 loads in flight
  STG(gA, &Abuf[0][0], 0); STG(gA + HSTEP, &Abuf[0][128 * 64], 0);
  STG(gB, &Bbuf[0][0], 0); STG(gB + HSTEP, &Bbuf[0][128 * 64], 0);
  STG(gB, &Bbuf[1][0], 1); STG(gB + HSTEP, &Bbuf[1][128 * 64], 1);
  SC_VMF;
  SC_BAR;

  const int nkt = 8192 / 64;
  for (int i = 0; i < nkt / 2; i++) {
    int kt1 = 2 * i + 1;
    int kt2 = 2 * i + 2; if (kt2 > nkt - 1) kt2 = nkt - 1;   // tail clamp
    int kt3 = 2 * i + 3; if (kt3 > nkt - 1) kt3 = nkt - 1;
    short8 aA[4][2], bb0[2][2], bb1[2][2];

    // ---- K-tile 2i (buf0) ----
    // P1
    DSA(A0, 0); DSB(B0, 0, bb0);
    STG(gA, &Abuf[1][0], kt1);
    SC_LGKM8; SC_BAR; SC_LGKM0; SC_P1; MMA(0, 0, bb0); SC_P0; SC_BAR;
    // P2
    DSB(B0, 1, bb1);
    STG(gA + HSTEP, &Abuf[1][128 * 64], kt1);
    SC_BAR; SC_LGKM0; SC_P1; MMA(0, 1, bb1); SC_P0; SC_BAR;
    // P3
    DSA(A0, 1);
    STG(gB, &Bbuf[0][0], kt2);
    SC_BAR; SC_LGKM0; SC_P1; MMA(1, 1, bb1); SC_P0; SC_BAR;
    // P4
    STG(gB + HSTEP, &Bbuf[0][128 * 64], kt2);
    SC_VMF; SC_BAR; SC_LGKM0; SC_P1; MMA(1, 0, bb0); SC_P0; SC_BAR;

    // ---- K-tile 2i+1 (buf1) ----
    // P5
    DSA(A1, 0); DSB(B1, 0, bb0);
    STG(gA, &Abuf[0][0], kt2);
    SC_LGKM8; SC_BAR; SC_LGKM0; SC_P1; MMA(0, 0, bb0); SC_P0; SC_BAR;
    // P6
    DSB(B1, 1, bb1);
    STG(gA + HSTEP, &Abuf[0][128 * 64], kt2);
    SC_BAR; SC_LGKM0; SC_P1; MMA(0, 1, bb1); SC_P0; SC_BAR;
    // P7
    DSA(A1, 1);
    STG(gB, &Bbuf[1][0], kt3);
    SC_BAR; SC_LGKM0; SC_P1; MMA(1, 1, bb1); SC_P0; SC_BAR;
    // P8
    STG(gB + HSTEP, &Bbuf[1][128 * 64], kt3);
    SC_VMF; SC_BAR; SC_LGKM0; SC_P1; MMA(1, 0, bb0); SC_P0; SC_BAR;
  }

  // epilogue: strict-lower mask + bf16 store
#pragma unroll
  for (int mt = 0; mt < 8; mt++)
#pragma unroll
    for (int nt = 0; nt < 4; nt++) {
      int gn = bn * 256 + wc * 64 + nt * 16 + lane15;
#pragma unroll
      for (int r = 0; r < 4; r++) {
        int gm = bm * 256 + wr * 128 + mt * 16 + quad * 4 + r;
        Sb[(long)gm * T + gn] = f2b(gm > gn ? acc[mt][nt][r] : 0.f);
      }
    }
}

// ---------------------------------------------------------------------------
__global__ __launch_bounds__(256) void trans_f32_bf16(
    const float* __restrict__ src, u16* __restrict__ dst, int R, int C)
{
  __shared__ float tile[32][33];
  long off = (long)blockIdx.z * R * C;
  const float* s = src + off;
  u16* d = dst + off;
  int lx = threadIdx.x & 31, ly = threadIdx.x >> 5;
  int c = blockIdx.x * 32 + lx;
#pragma unroll
  for (int p = 0; p < 32; p += 8)
    tile[ly + p][lx] = s[(long)(blockIdx.y * 32 + ly + p) * C + c];
  __syncthreads();
  int rr = blockIdx.y * 32 + lx;
#pragma unroll
  for (int p = 0; p < 32; p += 8)
    d[(long)(blockIdx.x * 32 + ly + p) * R + rr] = f2b(tile[lx][ly + p]);
}

__device__ __forceinline__ float block_sum(float v, float* red) {
#pragma unroll
  for (int o = 32; o > 0; o >>= 1) v += __shfl_down(v, o, 64);
  int lane = threadIdx.x & 63, wid = threadIdx.x >> 6;
  if (lane == 0) red[wid] = v;
  __syncthreads();
  float r = red[0] + red[1] + red[2] + red[3];
  __syncthreads();
  return r;
}

__global__ __launch_bounds__(256) void embed_ln(
    const int* __restrict__ idx, const float* __restrict__ embed,
    float* __restrict__ x, u16* __restrict__ xb, u16* __restrict__ xT, int T)
{
  __shared__ float red[4];
  int t = blockIdx.x, d = threadIdx.x;
  float v = embed[(long)idx[t] * 256 + d];
  float mu = block_sum(v, red) * (1.f / 256.f);
  float c = v - mu;
  float var = block_sum(c * c, red) * (1.f / 256.f);
  float o = c * rsqrtf(var + 1e-5f);
  x[(long)t * 256 + d] = o;
  xb[(long)t * 256 + d] = f2b(o);
  xT[(long)d * T + t] = f2b(o);
}

__global__ __launch_bounds__(256) void row_ln(
    const float* __restrict__ in, u16* __restrict__ out)
{
  __shared__ float red[4];
  long row = blockIdx.x;
  int d = threadIdx.x;
  float v = in[row * 256 + d];
  float mu = block_sum(v, red) * (1.f / 256.f);
  float c = v - mu;
  float var = block_sum(c * c, red) * (1.f / 256.f);
  out[row * 256 + d] = f2b(c * rsqrtf(var + 1e-5f));
}

__global__ __launch_bounds__(256) void resid_ln(
    const float* __restrict__ yMLP, float* __restrict__ x,
    u16* __restrict__ xb, u16* __restrict__ xT, int T)
{
  __shared__ float red[4];
  int t = blockIdx.x, d = threadIdx.x;
  float y = yMLP[(long)t * 256 + d];
  float mu1 = block_sum(y, red) * (1.f / 256.f);
  float c1 = y - mu1;
  float var1 = block_sum(c1 * c1, red) * (1.f / 256.f);
  float l1 = c1 * rsqrtf(var1 + 1e-5f);
  float v = x[(long)t * 256 + d] + l1;
  float mu2 = block_sum(v, red) * (1.f / 256.f);
  float c2 = v - mu2;
  float var2 = block_sum(c2 * c2, red) * (1.f / 256.f);
  float o = c2 * rsqrtf(var2 + 1e-5f);
  x[(long)t * 256 + d] = o;
  xb[(long)t * 256 + d] = f2b(o);
  xT[(long)d * T + t] = f2b(o);
}

// ---------------------------------------------------------------------------
extern "C" void kernel_launch(void* const* d_in, const int* in_sizes, int n_in,
                              void* d_out, int out_size, void* d_ws, size_t ws_size,
                              hipStream_t stream) {
  const int*   idx       = (const int*)d_in[0];
  const float* embed     = (const float*)d_in[1];
  const float* encoder   = (const float*)d_in[2];
  const float* encoder_v = (const float*)d_in[3];
  const float* decoder   = (const float*)d_in[4];
  const float* lm_head   = (const float*)d_in[5];
  const int T = in_sizes[0];                 // 2048
  const int D = 256, NH = 4, Nn = 8192, V = 256;

  char* ws = (char*)d_ws;
  size_t off = 0;
  auto alloc = [&](size_t bytes) -> void* {
    void* p = ws + off; off += (bytes + 255) & ~(size_t)255; return p;
  };
  float* x_f32   = (float*)alloc((size_t)T * D * 4);
  float* yMLP    = (float*)alloc((size_t)T * D * 4);
  float* yKV_f32 = (float*)alloc((size_t)NH * T * D * 4);
  u16* x_b    = (u16*)alloc((size_t)T * D * 2);
  u16* xT     = (u16*)alloc((size_t)T * D * 2);
  u16* yKV_b  = (u16*)alloc((size_t)NH * T * D * 2);
  u16* lmT    = (u16*)alloc((size_t)D * V * 2);
  u16* encT   = (u16*)alloc((size_t)NH * Nn * D * 2);
  u16* encvT  = (u16*)alloc((size_t)NH * Nn * D * 2);
  u16* decT   = (u16*)alloc((size_t)D * NH * Nn * 2);
  // head-batch ladder: pick largest HB in {4,2,1} whose QR+scores fit
  size_t per_head = ((size_t)T * T * 2 + 256) + ((size_t)T * Nn * 2 + 256);
  int HB = 4;
  while (HB > 1 && off + (size_t)HB * per_head > ws_size) HB >>= 1;
  u16* scores = (u16*)alloc((size_t)HB * T * T * 2);
  u16* QRxy   = (u16*)alloc((size_t)HB * T * Nn * 2);
  if (off > ws_size) return;

  // one-time weight prep: transpose to K-major bf16
  trans_f32_bf16<<<dim3(Nn / 32, D / 32, NH), 256, 0, stream>>>(encoder, encT, D, Nn);
  trans_f32_bf16<<<dim3(Nn / 32, D / 32, NH), 256, 0, stream>>>(encoder_v, encvT, D, Nn);
  trans_f32_bf16<<<dim3(D / 32, (NH * Nn) / 32, 1), 256, 0, stream>>>(decoder, decT, NH * Nn, D);
  trans_f32_bf16<<<dim3(V / 32, D / 32, 1), 256, 0, stream>>>(lm_head, lmT, D, V);

  embed_ln<<<T, 256, 0, stream>>>(idx, embed, x_f32, x_b, xT, T);

  const int nbm = T / 256, ntri = nbm * (nbm + 1) / 2;   // tril 256-tiles

  for (int l = 0; l < 2; l++) {
    hipMemsetAsync(yMLP, 0, (size_t)T * D * 4, stream);
    for (int h0 = 0; h0 < NH; h0 += HB) {
      // QR = rope(relu(x @ encoder[h]))  (rope fused in epilogue)
      gemm_bt<1><<<dim3(Nn / 128, T / 128, HB), 256, 0, stream>>>(
          x_b, encT + (size_t)h0 * Nn * D, QRxy,
          D, D, D, Nn, 1, 0L, (long)Nn * D, (long)T * Nn, 0);
      // scores = tril(QR QR^T, -1); flat tril grid + XCD-chunked swizzle
      gemm_scores8<<<dim3(ntri * HB, 1, 1), 512, 0, stream>>>(QRxy, scores, T, ntri);
      // yKV = scores @ x (split-K=8, atomic f32, triangular K-clamp)
      hipMemsetAsync(yKV_f32, 0, (size_t)HB * T * D * 4, stream);
      gemm_bt<3><<<dim3(D / 128, T / 128, HB * 8), 256, 0, stream>>>(
          scores, xT, yKV_f32,
          T, T, T, D, 8, (long)T * T, 0L, (long)T * D, 1);
      // yKV = ln(yKV)
      row_ln<<<HB * T, 256, 0, stream>>>(yKV_f32, yKV_b);
      // xy = relu(yKV @ encoder_v[h]) * unrope(QR), in-place over QR
      gemm_bt<4><<<dim3(Nn / 128, T / 128, HB), 256, 0, stream>>>(
          yKV_b, encvT + (size_t)h0 * Nn * D, QRxy,
          D, D, D, Nn, 1, (long)T * D, (long)Nn * D, (long)T * Nn, 0);
      // yMLP += xy @ decoder[h]  (split-K=4, atomic f32: halves RMW traffic
      // vs 8 while keeping 512 blocks = 2/CU for overlap)
      gemm_bt<3><<<dim3(D / 128, T / 128, HB * 4), 256, 0, stream>>>(
          QRxy, decT + (size_t)h0 * Nn, yMLP,
          Nn, Nn, NH * Nn, D, 4, (long)T * Nn, (long)Nn, 0L, 0);
    }
    resid_ln<<<T, 256, 0, stream>>>(yMLP, x_f32, x_b, xT, T);
  }

  // logits = x @ lm_head (f32 out)
  gemm_bt<0><<<dim3(V / 128, T / 128, 1), 256, 0, stream>>>(
      x_b, lmT, d_out, D, D, D, V, 1, 0L, 0L, 0L, 0);
}